// Round 1
// 2725.160 us; speedup vs baseline: 1.0306x; 1.0306x over previous
//
#include <hip/hip_runtime.h>
#include <hip/hip_bf16.h>

// Doubly-recurrent LSTM + gumbel-sigmoid gate, B=256,T=64,H=512,V=6207,YF=2048.
// Persistent kernel; 16 independent row-group pipelines. XCD-aware dynamic role
// assignment pins each jb weight slice to one XCD (per-XCD footprint ~2.2 MB <
// 4 MB L2). v2: barriers replaced by producer seq-publish + consumer poll
// (drain/flag overlap consumer work); hf gather (32KB) replaced by 1KB gate-bit
// gather + local Ac rebuild (As & mask, bit-exact); As/Az gathers widened to
// dwordx4 and issued together; bits RT hidden under Az@Whht half of stage C;
// hP double-buffered for barrier-free rewrite safety.

typedef __attribute__((ext_vector_type(8))) short short8;   // 8 bf16 = 1 MFMA operand
typedef __attribute__((ext_vector_type(4))) float floatx4;  // MFMA accumulator
typedef __attribute__((ext_vector_type(4))) unsigned int uintx4;

#define MFMA16(a, b, c) __builtin_amdgcn_mfma_f32_16x16x32_bf16(a, b, c, 0, 0, 0)
#define AGENT __HIP_MEMORY_SCOPE_AGENT
// s_getreg HWREG(XCC_ID=20, offset=0, size=32)  [measured: learn_hip m09]
#define HWREG_XCC_ID ((31u << 11) | (0u << 6) | 20u)

__device__ inline float bf2f(ushort u) {
    union { unsigned int u32; float f; } v; v.u32 = ((unsigned int)u) << 16; return v.f;
}
__device__ inline ushort f2bf(float f) {  // RNE, finite inputs only
    union { float f; unsigned int u; } v; v.f = f;
    return (ushort)((v.u + 0x7fffu + ((v.u >> 16) & 1u)) >> 16);
}
__device__ inline short8 ld8(const ushort* p) { return *(const short8*)p; }
__device__ inline float sigf(float x) { return 1.0f / (1.0f + expf(-x)); }
__device__ inline void mm3(floatx4& acc, short8 ah, short8 al, short8 bh, short8 bl) {
    acc = MFMA16(ah, bh, acc);
    acc = MFMA16(ah, bl, acc);
    acc = MFMA16(al, bh, acc);
}

// ---------------------------------------------------------------------------
// prep: split fp32 arrays into bf16 hi/lo in wreg; zero seqs/claim + state.
// zero region: bar[4128] + hP0 + hP1 + htP0 + htP1 (4*131072) = 528416 uints.
// ---------------------------------------------------------------------------
__global__ __launch_bounds__(256) void k_prep(const float* __restrict__ w0,
                                              const float* __restrict__ w1,
                                              const float* __restrict__ w2,
                                              const float* __restrict__ w3,
                                              const float* __restrict__ wg,
                                              const float* __restrict__ wl,
                                              const float* __restrict__ em,
                                              const float* __restrict__ yy,
                                              ushort* __restrict__ wreg,
                                              uint* __restrict__ zbase) {
    unsigned i = blockIdx.x * 256u + threadIdx.x;
    if (i >= 9866784u) return;
    if (i >= 9338368u) {
        zbase[i - 9338368u] = 0u;
        return;
    }
    const float* src; ushort* hi; unsigned n, loc;
    if (i < 4194304u) {
        unsigned seg = i >> 20; loc = i & 1048575u; n = 1048576u;
        hi = wreg + seg * 2097152u;
        src = (seg == 0) ? w0 : (seg == 1) ? w1 : (seg == 2) ? w2 : w3;
    } else if (i < 5505024u) { loc = i - 4194304u; src = wg; hi = wreg + 8388608u;  n = 1310720u; }
    else if (i < 5636096u)   { loc = i - 5505024u; src = wl; hi = wreg + 11010048u; n = 131072u; }
    else if (i < 8814080u)   { loc = i - 5636096u; src = em; hi = wreg + 11272192u; n = 3177984u; }
    else                     { loc = i - 8814080u; src = yy; hi = wreg + 17628160u; n = 524288u; }
    float v = src[loc];
    ushort h = f2bf(v);
    hi[loc] = h;
    hi[n + loc] = f2bf(v - bf2f(h));
}

// ---------------------------------------------------------------------------
// gy = y @ Wg[:,512:].T + bg  (M=256,N=512,K=2048; 256 blocks, 4-way K-split)
// ---------------------------------------------------------------------------
__global__ __launch_bounds__(512) void k_gy(const ushort* __restrict__ y_hi,
                                            const ushort* __restrict__ y_lo,
                                            const ushort* __restrict__ Wg_hi,
                                            const ushort* __restrict__ Wg_lo,
                                            const float* __restrict__ bg,
                                            float* __restrict__ gy) {
    __shared__ float zsB[4 * 528];
    int tid = threadIdx.x, lane = tid & 63, w = tid >> 6;
    int quad = lane >> 4, lr = lane & 15, q8 = quad * 8;
    int r0 = (blockIdx.x >> 4) * 16, n0 = (blockIdx.x & 15) * 32;
    int nh = w & 1, kq = w >> 1;
    int arow = r0 + lr, brow = n0 + nh * 16 + lr;
    floatx4 acc = {};
#pragma unroll
    for (int k0 = 0; k0 < 512; k0 += 32) {
        short8 ah = ld8(y_hi + arow * 2048 + kq * 512 + k0 + q8);
        short8 al = ld8(y_lo + arow * 2048 + kq * 512 + k0 + q8);
        short8 bh = ld8(Wg_hi + brow * 2560 + 512 + kq * 512 + k0 + q8);
        short8 bl = ld8(Wg_lo + brow * 2560 + 512 + kq * 512 + k0 + q8);
        mm3(acc, ah, al, bh, bl);
    }
#pragma unroll
    for (int r4 = 0; r4 < 4; r4++)
        zsB[kq * 528 + (quad * 4 + r4) * 33 + nh * 16 + lr] = acc[r4];
    __syncthreads();
    int ml = tid >> 5, jj = tid & 31;
    float s = zsB[ml * 33 + jj] + zsB[528 + ml * 33 + jj] +
              zsB[1056 + ml * 33 + jj] + zsB[1584 + ml * 33 + jj];
    gy[(r0 + ml) * 512 + n0 + jj] = s + bg[n0 + jj];
}

// ---------------------------------------------------------------------------
struct KP {
    const float *b_ih, *b_hh, *b_iht, *b_hht, *u1, *u2, *gy;
    const int* x;
    uint *hseq, *bseq;                // 16 groups x 16 seq words (one line each)
    uint* claim;                      // 8 XCDs x 16-uint stride claim counters
    uint *hP0, *hP1, *htP0, *htP1, *bitsP;
    ushort *ht_hi, *ht_lo;
    const ushort *Whh_hi, *Whh_lo, *Wih_hi, *Wih_lo;
    const ushort *Wiht_hi, *Wiht_lo, *Whht_hi, *Whht_lo;
    const ushort *Wg_hi, *Wg_lo, *em_hi, *em_lo;
};

// Producer publish: drain own wave's stores, block-sync (=> all waves drained),
// then one seq store. Consumers poll; no two-sided barrier.
__device__ inline void publish(uint* sq, uint v) {
    asm volatile("" ::: "memory");
    __builtin_amdgcn_s_waitcnt(0);
    __syncthreads();
    if (threadIdx.x == 0)
        __hip_atomic_store(sq, v, __ATOMIC_RELAXED, AGENT);
}
__device__ inline void poll16(const uint* sq, uint target) {
    if ((threadIdx.x >> 6) == 0) {
        int l = threadIdx.x & 63;
        for (;;) {
            uint v = (l < 16) ? __hip_atomic_load(&sq[l], __ATOMIC_RELAXED, AGENT) : target;
            if (__all((int)(v >= target))) break;
            __builtin_amdgcn_s_sleep(1);
        }
    }
    __syncthreads();
}

// Issue 16 rows x 64B gather of a packed (hi|lo<<16) [256][512] buffer as
// 4 x dwordx4 per thread (device-coherent, 2x MLP vs dwordx2 atomics).
__device__ inline void issue_row16(const uint* __restrict__ src, int r0, uintx4* v) {
    int tid = threadIdx.x;
    int sr = tid >> 5, scol = (tid & 31) * 16;
    const uint* pp = src + (r0 + sr) * 512 + scol;
    asm volatile(
        "global_load_dwordx4 %0, %4, off sc0 sc1\n\t"
        "global_load_dwordx4 %1, %4, off offset:16 sc0 sc1\n\t"
        "global_load_dwordx4 %2, %4, off offset:32 sc0 sc1\n\t"
        "global_load_dwordx4 %3, %4, off offset:48 sc0 sc1"
        : "=v"(v[0]), "=v"(v[1]), "=v"(v[2]), "=v"(v[3])
        : "v"(pp) : "memory");
}
__device__ inline void unpack_row16(const uintx4* v, ushort* __restrict__ dst) {
    int tid = threadIdx.x;
    int sr = tid >> 5, scol = (tid & 31) * 16;
    ushort* d = dst + sr * 1032;
#pragma unroll
    for (int i = 0; i < 4; i++) {
#pragma unroll
        for (int jp = 0; jp < 2; jp++) {
            uint u0 = v[i][jp * 2], u1v = v[i][jp * 2 + 1];
            int c = scol + i * 4 + jp * 2;
            *(uint*)(d + c) = (u0 & 0xffffu) | ((u1v & 0xffffu) << 16);
            *(uint*)(d + 520 + c) = (u0 >> 16) | (u1v & 0xffff0000u);
        }
    }
}

// Stage 16 emb rows (hi/lo planes, plain cached loads) into LDS, As layout.
__device__ inline void stage_emb(const ushort* __restrict__ emh,
                                 const ushort* __restrict__ eml,
                                 const int* __restrict__ x, int r0, int t,
                                 ushort* __restrict__ dst) {
    int tid = threadIdx.x;
    int sr = tid >> 5, sc = (tid & 31) * 16;
    int tok = x[(r0 + sr) * 64 + t];
    const short8* ph = (const short8*)(emh + (size_t)tok * 512 + sc);
    const short8* pl = (const short8*)(eml + (size_t)tok * 512 + sc);
    short8 h0 = ph[0], h1 = ph[1], l0 = pl[0], l1 = pl[1];
    ushort* d = dst + sr * 1032;
    *(short8*)(d + sc) = h0;       *(short8*)(d + sc + 8) = h1;
    *(short8*)(d + 520 + sc) = l0; *(short8*)(d + 520 + sc + 8) = l1;
}

__device__ inline short8 fragA(const ushort* As, int row, int k) {
    return *(const short8*)(As + row * 1032 + k);
}

__global__ void __launch_bounds__(512, 1) k_main(KP p) {
    __shared__ ushort As[16 * 1032];   // h(t) full tile (serves B(t) and A(t+1))
    __shared__ ushort Ae[16 * 1032];   // emb rows for current t
    __shared__ ushort Az[16 * 1032];   // ht(t-1) tile
    __shared__ ushort Ac[16 * 1032];   // hf tile, rebuilt locally = As & gate bits
    __shared__ float zs[16 * 132];     // A/C epilogue; B K-split partials
    __shared__ uint gbits[256];        // gate bits: 16 rows x 16 words
    __shared__ uint role_s;

    const int tid = threadIdx.x;           // 0..511
    const int w = tid >> 6;                // wave 0..7
    const int lane = tid & 63;
    const int quad = lane >> 4;
    const int lr = lane & 15;
    const int q8 = quad * 8;
    const float EPS = 1e-10f;

    // ---- XCD-aware role claim: jb pinned to XCD so weight slices stay
    // L2-resident regardless of hardware block->XCD mapping. LDS forces
    // 1 block/CU => exactly 32 blocks/XCD.
    if (tid == 0) {
        uint xcc = __builtin_amdgcn_s_getreg(HWREG_XCC_ID) & 7u;
        uint slot = __hip_atomic_fetch_add(&p.claim[xcc * 16], 1u,
                                           __ATOMIC_RELAXED, AGENT) & 31u;
        role_s = xcc * 32u + slot;
    }
    __syncthreads();
    const uint role = role_s;
    const int jb = (int)(role >> 4);       // xcc*2 + (slot>>4)
    const int g16 = (int)(role & 15u);
    const int r0 = g16 * 16, j0 = jb * 32;

    const int gate = w >> 1, nh = w & 1;
    const int brow = gate * 512 + j0 + nh * 16 + lr;   // stage A/C weight row
    const int kq = w >> 1;                              // stage B K-split window
    const int browB = j0 + nh * 16 + lr;                // stage B Wg row
    const int ml = tid >> 5, jj = tid & 31;             // epilogue element

    const float biasA = p.b_ih[brow] + p.b_hh[brow];
    const float biasC = p.b_iht[brow] + p.b_hht[brow];
    const float gy_r = p.gy[(r0 + ml) * 512 + j0 + jj];
    const ushort* WhhH = p.Whh_hi + brow * 512;
    const ushort* WhhL = p.Whh_lo + brow * 512;
    const ushort* WihH = p.Wih_hi + brow * 512;
    const ushort* WihL = p.Wih_lo + brow * 512;
    const ushort* WitH = p.Wiht_hi + brow * 512;
    const ushort* WitL = p.Wiht_lo + brow * 512;
    const ushort* WhtH = p.Whht_hi + brow * 512;
    const ushort* WhtL = p.Whht_lo + brow * 512;
    const ushort* WgH = p.Wg_hi + browB * 2560 + kq * 128;
    const ushort* WgL = p.Wg_lo + browB * 2560 + kq * 128;
    const float* pu1 = p.u1 + (r0 + ml) * 512 + j0 + jj;
    const float* pu2 = p.u2 + (r0 + ml) * 512 + j0 + jj;
    uint* hs = p.hseq + g16 * 16;      // this group's 64B seq lines
    uint* bs = p.bseq + g16 * 16;

    // init: h(-1) = 0 in As; emb rows for t=0 into Ae
    for (int i = tid; i < 16 * 1032; i += 512) As[i] = 0;
    stage_emb(p.em_hi, p.em_lo, p.x, r0, 0, Ae);
    __syncthreads();

    float c_reg = 0.0f, ct_reg = 0.0f;

    for (int t = 0; t < 64; t++) {
        // ==== Stage A: z1 = h@Whh.T + emb@Wih.T -> c, h ======================
        {
            floatx4 a1 = {}, a2 = {};
#pragma unroll
            for (int k0 = 0; k0 < 512; k0 += 32) {
                mm3(a1, fragA(As, lr, k0 + q8), fragA(As, lr, 520 + k0 + q8),
                    ld8(WhhH + k0 + q8), ld8(WhhL + k0 + q8));
                mm3(a2, fragA(Ae, lr, k0 + q8), fragA(Ae, lr, 520 + k0 + q8),
                    ld8(WihH + k0 + q8), ld8(WihL + k0 + q8));
            }
#pragma unroll
            for (int r4 = 0; r4 < 4; r4++)
                zs[(quad * 4 + r4) * 132 + gate * 32 + nh * 16 + lr] =
                    a1[r4] + a2[r4] + biasA;
        }
        __syncthreads();
        uint* hPcur = (t & 1) ? p.hP1 : p.hP0;   // double-buffered (no barriers)
        {
            float zi = zs[ml * 132 + jj],      zf = zs[ml * 132 + 32 + jj];
            float zg = zs[ml * 132 + 64 + jj], zo = zs[ml * 132 + 96 + jj];
            c_reg = sigf(zf) * c_reg + sigf(zi) * tanhf(zg);
            float hv = sigf(zo) * tanhf(c_reg);
            ushort hb = f2bf(hv);
            ushort lb = f2bf(hv - bf2f(hb));
            __hip_atomic_store(&hPcur[(r0 + ml) * 512 + j0 + jj],
                               (uint)hb | ((uint)lb << 16), __ATOMIC_RELAXED, AGENT);
        }
        // hseq also covers htP(t-1) stores (drained by the same waitcnt)
        publish(&hs[jb], (uint)(t + 1));
        // window work covers other producers' drain+flag latency
        float U1 = __builtin_nontemporal_load(pu1 + t * 131072);
        float U2 = __builtin_nontemporal_load(pu2 + t * 131072);
        float noise = -logf(logf(U2 + EPS) / logf(U1 + EPS) + EPS);
        poll16(hs, (uint)(t + 1));
        // ---- gather h(t) full + ht(t-1) full; overlap with emb(t+1) loads ---
        uintx4 va[4], vz[4];
        issue_row16(hPcur, r0, va);
        issue_row16((t & 1) ? p.htP0 : p.htP1, r0, vz);
        if (t < 63) stage_emb(p.em_hi, p.em_lo, p.x, r0, t + 1, Ae);
        asm volatile("s_waitcnt vmcnt(0)" ::: "memory");
        __builtin_amdgcn_sched_barrier(0);
        unpack_row16(va, As);
        unpack_row16(vz, Az);
        __syncthreads();

        // ==== Stage B: gate logits -> gate bits (published, 64B/block) =======
        {
            floatx4 acc = {};
#pragma unroll
            for (int k0 = 0; k0 < 128; k0 += 32)
                mm3(acc, fragA(As, lr, kq * 128 + k0 + q8),
                    fragA(As, lr, 520 + kq * 128 + k0 + q8),
                    ld8(WgH + k0 + q8), ld8(WgL + k0 + q8));
#pragma unroll
            for (int r4 = 0; r4 < 4; r4++)
                zs[kq * 528 + (quad * 4 + r4) * 33 + nh * 16 + lr] = acc[r4];
        }
        __syncthreads();
        {
            float z2 = zs[ml * 33 + jj] + zs[528 + ml * 33 + jj] +
                       zs[1056 + ml * 33 + jj] + zs[1584 + ml * 33 + jj];
            float logit = fmaxf(z2 + gy_r, 0.0f);
            bool gbit = sigf(logit + noise) >= 0.5f;
            unsigned long long bm = __ballot((int)gbit);
            if ((lane & 31) == 0)
                __hip_atomic_store(&p.bitsP[(r0 + ml) * 16 + jb],
                                   (uint)(bm >> ((lane >> 5) * 32)),
                                   __ATOMIC_RELAXED, AGENT);
        }
        publish(&bs[jb], (uint)(t + 1));

        // ==== Stage C: z3 = hf@Wiht.T + ht@Whht.T -> ct, ht ==================
        // c2 half 1 covers bseq-poll skew; bits load issued between halves so
        // half 2 covers its round trip.
        floatx4 c2a = {};
#pragma unroll
        for (int k0 = 0; k0 < 256; k0 += 32)
            mm3(c2a, fragA(Az, lr, k0 + q8), fragA(Az, lr, 520 + k0 + q8),
                ld8(WhtH + k0 + q8), ld8(WhtL + k0 + q8));
        poll16(bs, (uint)(t + 1));
        uint rb = 0;
        if (tid < 256)
            asm volatile("global_load_dword %0, %1, off sc0 sc1"
                         : "=v"(rb) : "v"(p.bitsP + r0 * 16 + tid) : "memory");
#pragma unroll
        for (int k0 = 256; k0 < 512; k0 += 32)
            mm3(c2a, fragA(Az, lr, k0 + q8), fragA(Az, lr, 520 + k0 + q8),
                ld8(WhtH + k0 + q8), ld8(WhtL + k0 + q8));
        asm volatile("s_waitcnt vmcnt(0)" ::: "memory");
        __builtin_amdgcn_sched_barrier(0);
        if (tid < 256) gbits[tid] = rb;
        __syncthreads();
        // build Ac = As & mask (bit-exact hf: gate is 0/1 on bf16 hi/lo pair)
        {
            int sr = tid >> 5, sc = (tid & 31) * 16;
            uint word = gbits[sr * 16 + (sc >> 5)];
            uint chunk = (word >> (sc & 16)) & 0xffffu;
            const ushort* as0 = As + sr * 1032 + sc;
            ushort* ac0 = Ac + sr * 1032 + sc;
#pragma unroll
            for (int j = 0; j < 16; j++) {
                ushort m = (ushort)(0u - ((chunk >> j) & 1u));
                ac0[j] = (ushort)(as0[j] & m);
                ac0[520 + j] = (ushort)(as0[520 + j] & m);
            }
        }
        __syncthreads();
        {
            floatx4 c1a = {};
#pragma unroll
            for (int k0 = 0; k0 < 512; k0 += 32)
                mm3(c1a, fragA(Ac, lr, k0 + q8), fragA(Ac, lr, 520 + k0 + q8),
                    ld8(WitH + k0 + q8), ld8(WitL + k0 + q8));
#pragma unroll
            for (int r4 = 0; r4 < 4; r4++)
                zs[(quad * 4 + r4) * 132 + gate * 32 + nh * 16 + lr] =
                    c1a[r4] + c2a[r4] + biasC;
        }
        __syncthreads();
        {
            float zi = zs[ml * 132 + jj],      zf = zs[ml * 132 + 32 + jj];
            float zg = zs[ml * 132 + 64 + jj], zo = zs[ml * 132 + 96 + jj];
            ct_reg = sigf(zf) * ct_reg + sigf(zi) * tanhf(zg);
            float hv = sigf(zo) * tanhf(ct_reg);
            ushort hb = f2bf(hv);
            ushort lb = f2bf(hv - bf2f(hb));
            int idx = (r0 + ml) * 512 + j0 + jj;
            uint* htcur = (t & 1) ? p.htP1 : p.htP0;
            __hip_atomic_store(&htcur[idx], (uint)hb | ((uint)lb << 16),
                               __ATOMIC_RELAXED, AGENT);
            if (t == 63) { p.ht_hi[idx] = hb; p.ht_lo[idx] = lb; }
        }
        __syncthreads();   // zs/As reuse safety within the block
    }
}

// ---------------------------------------------------------------------------
// out = relu(ht @ Wlin.T + blin)  (M=256,N=256,K=512 hi/lo) -> fp32
// ---------------------------------------------------------------------------
__global__ __launch_bounds__(256) void k_final(const ushort* __restrict__ ht_hi,
                                               const ushort* __restrict__ ht_lo,
                                               const ushort* __restrict__ Wl_hi,
                                               const ushort* __restrict__ Wl_lo,
                                               const float* __restrict__ blin,
                                               float* __restrict__ out) {
    int tid = threadIdx.x, lane = tid & 63, w = tid >> 6;
    int wm = w & 1, wn = w >> 1, quad = lane >> 4, lr = lane & 15;
    int m0 = blockIdx.y * 64, n0 = blockIdx.x * 64;
    floatx4 acc[2][2] = {};
    for (int k0 = 0; k0 < 512; k0 += 32) {
        short8 ah[2], al[2], bh[2], bl[2];
#pragma unroll
        for (int tn = 0; tn < 2; tn++) {
            int n = n0 + wn * 32 + tn * 16 + lr;
            bh[tn] = ld8(Wl_hi + n * 512 + k0 + quad * 8);
            bl[tn] = ld8(Wl_lo + n * 512 + k0 + quad * 8);
        }
#pragma unroll
        for (int tm = 0; tm < 2; tm++) {
            int r = m0 + wm * 32 + tm * 16 + lr;
            ah[tm] = ld8(ht_hi + r * 512 + k0 + quad * 8);
            al[tm] = ld8(ht_lo + r * 512 + k0 + quad * 8);
        }
#pragma unroll
        for (int tm = 0; tm < 2; tm++)
#pragma unroll
            for (int tn = 0; tn < 2; tn++) mm3(acc[tm][tn], ah[tm], al[tm], bh[tn], bl[tn]);
    }
#pragma unroll
    for (int tm = 0; tm < 2; tm++)
#pragma unroll
        for (int tn = 0; tn < 2; tn++)
#pragma unroll
            for (int r4 = 0; r4 < 4; r4++) {
                int row = m0 + wm * 32 + tm * 16 + quad * 4 + r4;
                int n = n0 + wn * 32 + tn * 16 + lr;
                out[row * 256 + n] = fmaxf(acc[tm][tn][r4] + blin[n], 0.0f);
            }
}

// ---------------------------------------------------------------------------
extern "C" void kernel_launch(void* const* d_in, const int* in_sizes, int n_in,
                              void* d_out, int out_size, void* d_ws, size_t ws_size,
                              hipStream_t stream) {
    (void)in_sizes; (void)n_in; (void)out_size; (void)ws_size;
    const float* y      = (const float*)d_in[0];
    const int*   x      = (const int*)d_in[1];
    const float* emb    = (const float*)d_in[2];
    const float* W_ih   = (const float*)d_in[3];
    const float* W_hh   = (const float*)d_in[4];
    const float* b_ih   = (const float*)d_in[5];
    const float* b_hh   = (const float*)d_in[6];
    const float* W_iht  = (const float*)d_in[7];
    const float* W_hht  = (const float*)d_in[8];
    const float* b_iht  = (const float*)d_in[9];
    const float* b_hht  = (const float*)d_in[10];
    const float* Wg     = (const float*)d_in[11];
    const float* bg     = (const float*)d_in[12];
    const float* Wlin   = (const float*)d_in[13];
    const float* blin   = (const float*)d_in[14];
    const float* u1     = (const float*)d_in[15];
    const float* u2     = (const float*)d_in[16];
    float* out = (float*)d_out;

    // ws layout (uints): bar[4128]=hseq(256)|bseq(256)|pad|claim(+1024)
    //                    hP0 hP1 htP0 htP1 [4x131072]  (zeroed with bar)
    //                    gy[131072 f32] ht_hi/ht_lo[131072 us] bitsP[4096] wreg
    uint* bar  = (uint*)d_ws;
    uint* hP0  = bar + 4128;
    uint* hP1  = hP0 + 131072;
    uint* htP0 = hP1 + 131072;
    uint* htP1 = htP0 + 131072;
    float* gy  = (float*)(htP1 + 131072);
    ushort* ht_hi = (ushort*)(gy + 131072);
    ushort* ht_lo = ht_hi + 131072;
    uint* bitsP = (uint*)(ht_lo + 131072);
    ushort* wreg = (ushort*)(bitsP + 4096);

    KP p;
    p.b_ih = b_ih; p.b_hh = b_hh; p.b_iht = b_iht; p.b_hht = b_hht;
    p.u1 = u1; p.u2 = u2; p.gy = gy; p.x = x;
    p.hseq = bar; p.bseq = bar + 256; p.claim = bar + 1024;
    p.hP0 = hP0; p.hP1 = hP1; p.htP0 = htP0; p.htP1 = htP1; p.bitsP = bitsP;
    p.ht_hi = ht_hi; p.ht_lo = ht_lo;
    p.Wih_hi  = wreg;             p.Wih_lo  = wreg + 1048576;
    p.Whh_hi  = wreg + 2097152;   p.Whh_lo  = wreg + 3145728;
    p.Wiht_hi = wreg + 4194304;   p.Wiht_lo = wreg + 5242880;
    p.Whht_hi = wreg + 6291456;   p.Whht_lo = wreg + 7340032;
    p.Wg_hi   = wreg + 8388608;   p.Wg_lo   = wreg + 9699328;
    p.em_hi   = wreg + 11272192;  p.em_lo   = wreg + 14450176;
    const ushort* Wl_hi = wreg + 11010048; const ushort* Wl_lo = wreg + 11141120;
    const ushort* y_hi  = wreg + 17628160; const ushort* y_lo  = wreg + 18152448;

    k_prep<<<dim3(38543), dim3(256), 0, stream>>>(W_ih, W_hh, W_iht, W_hht, Wg, Wlin,
                                                  emb, y, wreg, bar);
    k_gy<<<dim3(256), dim3(512), 0, stream>>>(y_hi, y_lo, p.Wg_hi, p.Wg_lo, bg, gy);

    void* args[] = {(void*)&p};
    hipLaunchCooperativeKernel((const void*)k_main, dim3(256), dim3(512), args, 0, stream);

    k_final<<<dim3(4, 4), dim3(256), 0, stream>>>(ht_hi, ht_lo, Wl_hi, Wl_lo, blin, out);
}

// Round 2
// 2589.794 us; speedup vs baseline: 1.0845x; 1.0523x over previous
//
#include <hip/hip_runtime.h>
#include <hip/hip_bf16.h>

// Doubly-recurrent LSTM + gumbel-sigmoid gate, B=256,T=64,H=512,V=6207,YF=2048.
// Persistent kernel; 16 independent row-group pipelines. XCD-aware dynamic role
// assignment pins each jb weight slice to one XCD (~2.2 MB < 4 MB L2).
// v3: team-split stage A (waves 0-3 a1, waves 4-7 a2) halves redundant LDS
// fragment reads; third seq line (tseq) lets the Az gather issue right after
// the A matmuls (RT hidden under epi-A + h-drain); c2 is a 3-way cover
// (hs-flag / As-RT / bs-flag windows); U1/U2 prefetched a step ahead; emb
// staging covers the bits drain; counted vmcnt for the bits gather.
// All MFMA accumulation chains and epilogue add orders are bit-identical to v2.

typedef __attribute__((ext_vector_type(8))) short short8;   // 8 bf16 = 1 MFMA operand
typedef __attribute__((ext_vector_type(4))) float floatx4;  // MFMA accumulator
typedef __attribute__((ext_vector_type(4))) unsigned int uintx4;

#define MFMA16(a, b, c) __builtin_amdgcn_mfma_f32_16x16x32_bf16(a, b, c, 0, 0, 0)
#define AGENT __HIP_MEMORY_SCOPE_AGENT
// s_getreg HWREG(XCC_ID=20, offset=0, size=32)  [measured: learn_hip m09]
#define HWREG_XCC_ID ((31u << 11) | (0u << 6) | 20u)

__device__ inline float bf2f(ushort u) {
    union { unsigned int u32; float f; } v; v.u32 = ((unsigned int)u) << 16; return v.f;
}
__device__ inline ushort f2bf(float f) {  // RNE, finite inputs only
    union { float f; unsigned int u; } v; v.f = f;
    return (ushort)((v.u + 0x7fffu + ((v.u >> 16) & 1u)) >> 16);
}
__device__ inline short8 ld8(const ushort* p) { return *(const short8*)p; }
__device__ inline float sigf(float x) { return 1.0f / (1.0f + expf(-x)); }
__device__ inline void mm3(floatx4& acc, short8 ah, short8 al, short8 bh, short8 bl) {
    acc = MFMA16(ah, bh, acc);
    acc = MFMA16(ah, bl, acc);
    acc = MFMA16(al, bh, acc);
}

// ---------------------------------------------------------------------------
// prep: split fp32 arrays into bf16 hi/lo in wreg; zero seqs/claim + state.
// zero region: bar[4128] + hP0 + hP1 + htP0 + htP1 (4*131072) = 528416 uints.
// ---------------------------------------------------------------------------
__global__ __launch_bounds__(256) void k_prep(const float* __restrict__ w0,
                                              const float* __restrict__ w1,
                                              const float* __restrict__ w2,
                                              const float* __restrict__ w3,
                                              const float* __restrict__ wg,
                                              const float* __restrict__ wl,
                                              const float* __restrict__ em,
                                              const float* __restrict__ yy,
                                              ushort* __restrict__ wreg,
                                              uint* __restrict__ zbase) {
    unsigned i = blockIdx.x * 256u + threadIdx.x;
    if (i >= 9866784u) return;
    if (i >= 9338368u) {
        zbase[i - 9338368u] = 0u;
        return;
    }
    const float* src; ushort* hi; unsigned n, loc;
    if (i < 4194304u) {
        unsigned seg = i >> 20; loc = i & 1048575u; n = 1048576u;
        hi = wreg + seg * 2097152u;
        src = (seg == 0) ? w0 : (seg == 1) ? w1 : (seg == 2) ? w2 : w3;
    } else if (i < 5505024u) { loc = i - 4194304u; src = wg; hi = wreg + 8388608u;  n = 1310720u; }
    else if (i < 5636096u)   { loc = i - 5505024u; src = wl; hi = wreg + 11010048u; n = 131072u; }
    else if (i < 8814080u)   { loc = i - 5636096u; src = em; hi = wreg + 11272192u; n = 3177984u; }
    else                     { loc = i - 8814080u; src = yy; hi = wreg + 17628160u; n = 524288u; }
    float v = src[loc];
    ushort h = f2bf(v);
    hi[loc] = h;
    hi[n + loc] = f2bf(v - bf2f(h));
}

// ---------------------------------------------------------------------------
// gy = y @ Wg[:,512:].T + bg  (M=256,N=512,K=2048; 256 blocks, 4-way K-split)
// ---------------------------------------------------------------------------
__global__ __launch_bounds__(512) void k_gy(const ushort* __restrict__ y_hi,
                                            const ushort* __restrict__ y_lo,
                                            const ushort* __restrict__ Wg_hi,
                                            const ushort* __restrict__ Wg_lo,
                                            const float* __restrict__ bg,
                                            float* __restrict__ gy) {
    __shared__ float zsB[4 * 528];
    int tid = threadIdx.x, lane = tid & 63, w = tid >> 6;
    int quad = lane >> 4, lr = lane & 15, q8 = quad * 8;
    int r0 = (blockIdx.x >> 4) * 16, n0 = (blockIdx.x & 15) * 32;
    int nh = w & 1, kq = w >> 1;
    int arow = r0 + lr, brow = n0 + nh * 16 + lr;
    floatx4 acc = {};
#pragma unroll
    for (int k0 = 0; k0 < 512; k0 += 32) {
        short8 ah = ld8(y_hi + arow * 2048 + kq * 512 + k0 + q8);
        short8 al = ld8(y_lo + arow * 2048 + kq * 512 + k0 + q8);
        short8 bh = ld8(Wg_hi + brow * 2560 + 512 + kq * 512 + k0 + q8);
        short8 bl = ld8(Wg_lo + brow * 2560 + 512 + kq * 512 + k0 + q8);
        mm3(acc, ah, al, bh, bl);
    }
#pragma unroll
    for (int r4 = 0; r4 < 4; r4++)
        zsB[kq * 528 + (quad * 4 + r4) * 33 + nh * 16 + lr] = acc[r4];
    __syncthreads();
    int ml = tid >> 5, jj = tid & 31;
    float s = zsB[ml * 33 + jj] + zsB[528 + ml * 33 + jj] +
              zsB[1056 + ml * 33 + jj] + zsB[1584 + ml * 33 + jj];
    gy[(r0 + ml) * 512 + n0 + jj] = s + bg[n0 + jj];
}

// ---------------------------------------------------------------------------
struct KP {
    const float *b_ih, *b_hh, *b_iht, *b_hht, *u1, *u2, *gy;
    const int* x;
    uint *hseq, *bseq, *tseq;         // 16 groups x 16 seq words (one line each)
    uint* claim;                      // 8 XCDs x 16-uint stride claim counters
    uint *hP0, *hP1, *htP0, *htP1, *bitsP;
    ushort *ht_hi, *ht_lo;
    const ushort *Whh_hi, *Whh_lo, *Wih_hi, *Wih_lo;
    const ushort *Wiht_hi, *Wiht_lo, *Whht_hi, *Whht_lo;
    const ushort *Wg_hi, *Wg_lo, *em_hi, *em_lo;
};

// Producer publish: drain own wave's stores, block-sync (=> all waves drained),
// then one seq store. Consumers poll; no two-sided barrier.
__device__ inline void publish(uint* sq, uint v) {
    asm volatile("" ::: "memory");
    __builtin_amdgcn_s_waitcnt(0);
    __syncthreads();
    if (threadIdx.x == 0)
        __hip_atomic_store(sq, v, __ATOMIC_RELAXED, AGENT);
}
__device__ inline void poll16(const uint* sq, uint target) {
    if ((threadIdx.x >> 6) == 0) {
        int l = threadIdx.x & 63;
        for (;;) {
            uint v = (l < 16) ? __hip_atomic_load(&sq[l], __ATOMIC_RELAXED, AGENT) : target;
            if (__all((int)(v >= target))) break;
            __builtin_amdgcn_s_sleep(1);
        }
    }
    __syncthreads();
}

// Issue 16 rows x 64B gather of a packed (hi|lo<<16) [256][512] buffer as
// 4 x dwordx4 per thread (device-coherent).
__device__ inline void issue_row16(const uint* __restrict__ src, int r0, uintx4* v) {
    int tid = threadIdx.x;
    int sr = tid >> 5, scol = (tid & 31) * 16;
    const uint* pp = src + (r0 + sr) * 512 + scol;
    asm volatile(
        "global_load_dwordx4 %0, %4, off sc0 sc1\n\t"
        "global_load_dwordx4 %1, %4, off offset:16 sc0 sc1\n\t"
        "global_load_dwordx4 %2, %4, off offset:32 sc0 sc1\n\t"
        "global_load_dwordx4 %3, %4, off offset:48 sc0 sc1"
        : "=v"(v[0]), "=v"(v[1]), "=v"(v[2]), "=v"(v[3])
        : "v"(pp) : "memory");
}
__device__ inline void unpack_row16(const uintx4* v, ushort* __restrict__ dst) {
    int tid = threadIdx.x;
    int sr = tid >> 5, scol = (tid & 31) * 16;
    ushort* d = dst + sr * 1032;
#pragma unroll
    for (int i = 0; i < 4; i++) {
#pragma unroll
        for (int jp = 0; jp < 2; jp++) {
            uint u0 = v[i][jp * 2], u1v = v[i][jp * 2 + 1];
            int c = scol + i * 4 + jp * 2;
            *(uint*)(d + c) = (u0 & 0xffffu) | ((u1v & 0xffffu) << 16);
            *(uint*)(d + 520 + c) = (u0 >> 16) | (u1v & 0xffff0000u);
        }
    }
}

// Stage 16 emb rows (hi/lo planes, plain cached loads) into LDS, As layout.
__device__ inline void stage_emb(const ushort* __restrict__ emh,
                                 const ushort* __restrict__ eml,
                                 const int* __restrict__ x, int r0, int t,
                                 ushort* __restrict__ dst) {
    int tid = threadIdx.x;
    int sr = tid >> 5, sc = (tid & 31) * 16;
    int tok = x[(r0 + sr) * 64 + t];
    const short8* ph = (const short8*)(emh + (size_t)tok * 512 + sc);
    const short8* pl = (const short8*)(eml + (size_t)tok * 512 + sc);
    short8 h0 = ph[0], h1 = ph[1], l0 = pl[0], l1 = pl[1];
    ushort* d = dst + sr * 1032;
    *(short8*)(d + sc) = h0;       *(short8*)(d + sc + 8) = h1;
    *(short8*)(d + 520 + sc) = l0; *(short8*)(d + 520 + sc + 8) = l1;
}

__device__ inline short8 fragA(const ushort* As, int row, int k) {
    return *(const short8*)(As + row * 1032 + k);
}

__global__ void __launch_bounds__(512, 1) k_main(KP p) {
    __shared__ ushort As[16 * 1032];   // h(t) full tile (serves B(t) and A(t+1))
    __shared__ ushort Ae[16 * 1032];   // emb rows for current t
    __shared__ ushort Az[16 * 1032];   // ht(t-1) tile
    __shared__ ushort Ac[16 * 1032];   // hf tile, rebuilt locally = As & gate bits
    __shared__ float zsD[4224];        // [0:2112] a1/zsB/c1 ; [2112:4224] a2/c2
    __shared__ uint gbits[256];        // gate bits: 16 rows x 16 words
    __shared__ uint role_s;

    const int tid = threadIdx.x;           // 0..511
    const int w = tid >> 6;                // wave 0..7
    const int lane = tid & 63;
    const int quad = lane >> 4;
    const int lr = lane & 15;
    const int q8 = quad * 8;
    const float EPS = 1e-10f;

    // ---- XCD-aware role claim: jb pinned to XCD so weight slices stay
    // L2-resident regardless of hardware block->XCD mapping. LDS forces
    // 1 block/CU => exactly 32 blocks/XCD.
    if (tid == 0) {
        uint xcc = __builtin_amdgcn_s_getreg(HWREG_XCC_ID) & 7u;
        uint slot = __hip_atomic_fetch_add(&p.claim[xcc * 16], 1u,
                                           __ATOMIC_RELAXED, AGENT) & 31u;
        role_s = xcc * 32u + slot;
    }
    __syncthreads();
    const uint role = role_s;
    const int jb = (int)(role >> 4);       // xcc*2 + (slot>>4)
    const int g16 = (int)(role & 15u);
    const int r0 = g16 * 16, j0 = jb * 32;

    // roles: team-split A (g4 = gate, team: 0 -> a1 (As@Whh), 1 -> a2 (Ae@Wih));
    // v2-style (gate, nh) for B/c1/c2.
    const int g4 = w & 3, team = w >> 2;
    const int gate = w >> 1, nh = w & 1;
    const int brow = gate * 512 + j0 + nh * 16 + lr;   // c1/c2 weight row
    const int kq = w >> 1;                              // stage B K-split window
    const int browB = j0 + nh * 16 + lr;                // stage B Wg row
    const int ml = tid >> 5, jj = tid & 31;             // epilogue element

    // epilogue-side biases (4 gates each), hoisted
    const float biasAe0 = p.b_ih[j0 + jj]        + p.b_hh[j0 + jj];
    const float biasAe1 = p.b_ih[512 + j0 + jj]  + p.b_hh[512 + j0 + jj];
    const float biasAe2 = p.b_ih[1024 + j0 + jj] + p.b_hh[1024 + j0 + jj];
    const float biasAe3 = p.b_ih[1536 + j0 + jj] + p.b_hh[1536 + j0 + jj];
    const float biasCe0 = p.b_iht[j0 + jj]        + p.b_hht[j0 + jj];
    const float biasCe1 = p.b_iht[512 + j0 + jj]  + p.b_hht[512 + j0 + jj];
    const float biasCe2 = p.b_iht[1024 + j0 + jj] + p.b_hht[1024 + j0 + jj];
    const float biasCe3 = p.b_iht[1536 + j0 + jj] + p.b_hht[1536 + j0 + jj];
    const float gy_r = p.gy[(r0 + ml) * 512 + j0 + jj];

    const int rowA = g4 * 512 + j0 + lr;               // team-A weight base row
    const ushort* WAh = (team ? p.Wih_hi : p.Whh_hi) + rowA * 512;
    const ushort* WAl = (team ? p.Wih_lo : p.Whh_lo) + rowA * 512;
    const ushort* WitH = p.Wiht_hi + brow * 512;       // c1
    const ushort* WitL = p.Wiht_lo + brow * 512;
    const ushort* WhtH = p.Whht_hi + brow * 512;       // c2
    const ushort* WhtL = p.Whht_lo + brow * 512;
    const ushort* WgH = p.Wg_hi + browB * 2560 + kq * 128;
    const ushort* WgL = p.Wg_lo + browB * 2560 + kq * 128;
    const float* pu1 = p.u1 + (r0 + ml) * 512 + j0 + jj;
    const float* pu2 = p.u2 + (r0 + ml) * 512 + j0 + jj;
    uint* hs = p.hseq + g16 * 16;      // this group's 64B seq lines
    uint* bs = p.bseq + g16 * 16;
    uint* hts = p.tseq + g16 * 16;

    // init: h(-1) = 0 in As; emb rows for t=0 into Ae; U(0) prefetch
    for (int i = tid; i < 16 * 1032; i += 512) As[i] = 0;
    stage_emb(p.em_hi, p.em_lo, p.x, r0, 0, Ae);
    float U1 = __builtin_nontemporal_load(pu1);
    float U2 = __builtin_nontemporal_load(pu2);
    __syncthreads();

    float c_reg = 0.0f, ct_reg = 0.0f;

    for (int t = 0; t < 64; t++) {
        // ==== Stage A (team-split): a1 = h@Whh.T (L), a2 = emb@Wih.T (H) =====
        {
            const ushort* Ax = team ? Ae : As;
            floatx4 acc0 = {}, acc1 = {};
#pragma unroll
            for (int k0 = 0; k0 < 512; k0 += 32) {
                short8 xh = fragA(Ax, lr, k0 + q8);
                short8 xl = fragA(Ax, lr, 520 + k0 + q8);
                mm3(acc0, xh, xl, ld8(WAh + k0 + q8), ld8(WAl + k0 + q8));
                mm3(acc1, xh, xl, ld8(WAh + 8192 + k0 + q8), ld8(WAl + 8192 + k0 + q8));
            }
#pragma unroll
            for (int r4 = 0; r4 < 4; r4++) {
                zsD[team * 2112 + (quad * 4 + r4) * 132 + g4 * 32 + lr]      = acc0[r4];
                zsD[team * 2112 + (quad * 4 + r4) * 132 + g4 * 32 + 16 + lr] = acc1[r4];
            }
        }
        // tseq flags propagated during stage A -> poll is ~instant; its
        // syncthreads doubles as the zsD visibility barrier.
        if (t > 0) poll16(hts, (uint)t); else __syncthreads();
        uintx4 vz[4];
        issue_row16((t & 1) ? p.htP0 : p.htP1, r0, vz);   // ht(t-1); RT hidden
        // ==== epi-A ====
        uint* hPcur = (t & 1) ? p.hP1 : p.hP0;   // double-buffered
        {
            float zi = (zsD[ml * 132 + jj]      + zsD[2112 + ml * 132 + jj])      + biasAe0;
            float zf = (zsD[ml * 132 + 32 + jj] + zsD[2112 + ml * 132 + 32 + jj]) + biasAe1;
            float zg = (zsD[ml * 132 + 64 + jj] + zsD[2112 + ml * 132 + 64 + jj]) + biasAe2;
            float zo = (zsD[ml * 132 + 96 + jj] + zsD[2112 + ml * 132 + 96 + jj]) + biasAe3;
            c_reg = sigf(zf) * c_reg + sigf(zi) * tanhf(zg);
            float hv = sigf(zo) * tanhf(c_reg);
            ushort hb = f2bf(hv);
            ushort lb = f2bf(hv - bf2f(hb));
            __hip_atomic_store(&hPcur[(r0 + ml) * 512 + j0 + jj],
                               (uint)hb | ((uint)lb << 16), __ATOMIC_RELAXED, AGENT);
        }
        // ---- publish hs (Az unpack folded into the drain window) ----
        asm volatile("s_waitcnt vmcnt(0)" ::: "memory");   // drains h stores + vz
        __builtin_amdgcn_sched_barrier(0);
        unpack_row16(vz, Az);
        __syncthreads();
        if (tid == 0)
            __hip_atomic_store(&hs[jb], (uint)(t + 1), __ATOMIC_RELAXED, AGENT);
        // noise for this step (U prefetched at t-1) -- pure VALU cover
        float noise = -logf(logf(U2 + EPS) / logf(U1 + EPS) + EPS);
        // c2 p1 [0,192): covers hs flag propagation
        floatx4 c2acc = {};
#pragma unroll
        for (int k0 = 0; k0 < 192; k0 += 32)
            mm3(c2acc, fragA(Az, lr, k0 + q8), fragA(Az, lr, 520 + k0 + q8),
                ld8(WhtH + k0 + q8), ld8(WhtL + k0 + q8));
        poll16(hs, (uint)(t + 1));
        uintx4 va[4];
        issue_row16(hPcur, r0, va);                        // h(t) full
        // c2 p2 [192,384): covers As gather RT
#pragma unroll
        for (int k0 = 192; k0 < 384; k0 += 32)
            mm3(c2acc, fragA(Az, lr, k0 + q8), fragA(Az, lr, 520 + k0 + q8),
                ld8(WhtH + k0 + q8), ld8(WhtL + k0 + q8));
        asm volatile("s_waitcnt vmcnt(0)" ::: "memory");
        __builtin_amdgcn_sched_barrier(0);
        unpack_row16(va, As);
        __syncthreads();

        // ==== Stage B: gate logits -> gate bits (published, 64B/block) =======
        {
            floatx4 acc = {};
#pragma unroll
            for (int k0 = 0; k0 < 128; k0 += 32)
                mm3(acc, fragA(As, lr, kq * 128 + k0 + q8),
                    fragA(As, lr, 520 + kq * 128 + k0 + q8),
                    ld8(WgH + k0 + q8), ld8(WgL + k0 + q8));
#pragma unroll
            for (int r4 = 0; r4 < 4; r4++)
                zsD[kq * 528 + (quad * 4 + r4) * 33 + nh * 16 + lr] = acc[r4];
        }
        __syncthreads();
        {
            float z2 = zsD[ml * 33 + jj] + zsD[528 + ml * 33 + jj] +
                       zsD[1056 + ml * 33 + jj] + zsD[1584 + ml * 33 + jj];
            float logit = fmaxf(z2 + gy_r, 0.0f);
            bool gbit = sigf(logit + noise) >= 0.5f;
            unsigned long long bm = __ballot((int)gbit);
            if ((lane & 31) == 0)
                __hip_atomic_store(&p.bitsP[(r0 + ml) * 16 + jb],
                                   (uint)(bm >> ((lane >> 5) * 32)),
                                   __ATOMIC_RELAXED, AGENT);
        }
        if (t < 63) stage_emb(p.em_hi, p.em_lo, p.x, r0, t + 1, Ae);  // covers bits drain
        publish(&bs[jb], (uint)(t + 1));
        // c2 p3 [384,512): covers bs flag propagation
#pragma unroll
        for (int k0 = 384; k0 < 512; k0 += 32)
            mm3(c2acc, fragA(Az, lr, k0 + q8), fragA(Az, lr, 520 + k0 + q8),
                ld8(WhtH + k0 + q8), ld8(WhtL + k0 + q8));
#pragma unroll
        for (int r4 = 0; r4 < 4; r4++)
            zsD[2112 + (quad * 4 + r4) * 132 + gate * 32 + nh * 16 + lr] = c2acc[r4];
        poll16(bs, (uint)(t + 1));
        uint rb = 0;
        if (tid < 256)
            asm volatile("global_load_dword %0, %1, off sc0 sc1"
                         : "=v"(rb) : "v"(p.bitsP + r0 * 16 + tid) : "memory");
        if (t < 63) {   // U prefetch for t+1 after the bits load -> counted wait
            U1 = __builtin_nontemporal_load(pu1 + (t + 1) * 131072);
            U2 = __builtin_nontemporal_load(pu2 + (t + 1) * 131072);
            asm volatile("s_waitcnt vmcnt(2)" ::: "memory");
        } else {
            asm volatile("s_waitcnt vmcnt(0)" ::: "memory");
        }
        __builtin_amdgcn_sched_barrier(0);
        if (tid < 256) gbits[tid] = rb;
        __syncthreads();
        // build Ac = As & mask (bit-exact hf: gate is 0/1 on bf16 hi/lo pair)
        {
            int sr = tid >> 5, sc = (tid & 31) * 16;
            uint word = gbits[sr * 16 + (sc >> 5)];
            uint chunk = (word >> (sc & 16)) & 0xffffu;
            const ushort* as0 = As + sr * 1032 + sc;
            ushort* ac0 = Ac + sr * 1032 + sc;
#pragma unroll
            for (int j = 0; j < 16; j++) {
                ushort m = (ushort)(0u - ((chunk >> j) & 1u));
                ac0[j] = (ushort)(as0[j] & m);
                ac0[520 + j] = (ushort)(as0[520 + j] & m);
            }
        }
        __syncthreads();
        // ==== c1 = hf@Wiht.T (all 8 waves, v2 chains) ========================
        {
            floatx4 c1acc = {};
#pragma unroll
            for (int k0 = 0; k0 < 512; k0 += 32)
                mm3(c1acc, fragA(Ac, lr, k0 + q8), fragA(Ac, lr, 520 + k0 + q8),
                    ld8(WitH + k0 + q8), ld8(WitL + k0 + q8));
#pragma unroll
            for (int r4 = 0; r4 < 4; r4++)
                zsD[(quad * 4 + r4) * 132 + gate * 32 + nh * 16 + lr] = c1acc[r4];
        }
        __syncthreads();
        // ==== epi-C ====
        {
            float zi = (zsD[ml * 132 + jj]      + zsD[2112 + ml * 132 + jj])      + biasCe0;
            float zf = (zsD[ml * 132 + 32 + jj] + zsD[2112 + ml * 132 + 32 + jj]) + biasCe1;
            float zg = (zsD[ml * 132 + 64 + jj] + zsD[2112 + ml * 132 + 64 + jj]) + biasCe2;
            float zo = (zsD[ml * 132 + 96 + jj] + zsD[2112 + ml * 132 + 96 + jj]) + biasCe3;
            ct_reg = sigf(zf) * ct_reg + sigf(zi) * tanhf(zg);
            float hv = sigf(zo) * tanhf(ct_reg);
            ushort hb = f2bf(hv);
            ushort lb = f2bf(hv - bf2f(hb));
            int idx = (r0 + ml) * 512 + j0 + jj;
            uint* htcur = (t & 1) ? p.htP1 : p.htP0;
            __hip_atomic_store(&htcur[idx], (uint)hb | ((uint)lb << 16),
                               __ATOMIC_RELAXED, AGENT);
            if (t == 63) { p.ht_hi[idx] = hb; p.ht_lo[idx] = lb; }
        }
        publish(&hts[jb], (uint)(t + 1));  // drains ht stores; sync guards LDS reuse
    }
}

// ---------------------------------------------------------------------------
// out = relu(ht @ Wlin.T + blin)  (M=256,N=256,K=512 hi/lo) -> fp32
// ---------------------------------------------------------------------------
__global__ __launch_bounds__(256) void k_final(const ushort* __restrict__ ht_hi,
                                               const ushort* __restrict__ ht_lo,
                                               const ushort* __restrict__ Wl_hi,
                                               const ushort* __restrict__ Wl_lo,
                                               const float* __restrict__ blin,
                                               float* __restrict__ out) {
    int tid = threadIdx.x, lane = tid & 63, w = tid >> 6;
    int wm = w & 1, wn = w >> 1, quad = lane >> 4, lr = lane & 15;
    int m0 = blockIdx.y * 64, n0 = blockIdx.x * 64;
    floatx4 acc[2][2] = {};
    for (int k0 = 0; k0 < 512; k0 += 32) {
        short8 ah[2], al[2], bh[2], bl[2];
#pragma unroll
        for (int tn = 0; tn < 2; tn++) {
            int n = n0 + wn * 32 + tn * 16 + lr;
            bh[tn] = ld8(Wl_hi + n * 512 + k0 + quad * 8);
            bl[tn] = ld8(Wl_lo + n * 512 + k0 + quad * 8);
        }
#pragma unroll
        for (int tm = 0; tm < 2; tm++) {
            int r = m0 + wm * 32 + tm * 16 + lr;
            ah[tm] = ld8(ht_hi + r * 512 + k0 + quad * 8);
            al[tm] = ld8(ht_lo + r * 512 + k0 + quad * 8);
        }
#pragma unroll
        for (int tm = 0; tm < 2; tm++)
#pragma unroll
            for (int tn = 0; tn < 2; tn++) mm3(acc[tm][tn], ah[tm], al[tm], bh[tn], bl[tn]);
    }
#pragma unroll
    for (int tm = 0; tm < 2; tm++)
#pragma unroll
        for (int tn = 0; tn < 2; tn++)
#pragma unroll
            for (int r4 = 0; r4 < 4; r4++) {
                int row = m0 + wm * 32 + tm * 16 + quad * 4 + r4;
                int n = n0 + wn * 32 + tn * 16 + lr;
                out[row * 256 + n] = fmaxf(acc[tm][tn][r4] + blin[n], 0.0f);
            }
}

// ---------------------------------------------------------------------------
extern "C" void kernel_launch(void* const* d_in, const int* in_sizes, int n_in,
                              void* d_out, int out_size, void* d_ws, size_t ws_size,
                              hipStream_t stream) {
    (void)in_sizes; (void)n_in; (void)out_size; (void)ws_size;
    const float* y      = (const float*)d_in[0];
    const int*   x      = (const int*)d_in[1];
    const float* emb    = (const float*)d_in[2];
    const float* W_ih   = (const float*)d_in[3];
    const float* W_hh   = (const float*)d_in[4];
    const float* b_ih   = (const float*)d_in[5];
    const float* b_hh   = (const float*)d_in[6];
    const float* W_iht  = (const float*)d_in[7];
    const float* W_hht  = (const float*)d_in[8];
    const float* b_iht  = (const float*)d_in[9];
    const float* b_hht  = (const float*)d_in[10];
    const float* Wg     = (const float*)d_in[11];
    const float* bg     = (const float*)d_in[12];
    const float* Wlin   = (const float*)d_in[13];
    const float* blin   = (const float*)d_in[14];
    const float* u1     = (const float*)d_in[15];
    const float* u2     = (const float*)d_in[16];
    float* out = (float*)d_out;

    // ws layout (uints): bar[4128]=hseq(256)|bseq(256)|tseq(256)|pad|claim(+1024)
    //                    hP0 hP1 htP0 htP1 [4x131072]  (zeroed with bar)
    //                    gy[131072 f32] ht_hi/ht_lo[131072 us] bitsP[4096] wreg
    uint* bar  = (uint*)d_ws;
    uint* hP0  = bar + 4128;
    uint* hP1  = hP0 + 131072;
    uint* htP0 = hP1 + 131072;
    uint* htP1 = htP0 + 131072;
    float* gy  = (float*)(htP1 + 131072);
    ushort* ht_hi = (ushort*)(gy + 131072);
    ushort* ht_lo = ht_hi + 131072;
    uint* bitsP = (uint*)(ht_lo + 131072);
    ushort* wreg = (ushort*)(bitsP + 4096);

    KP p;
    p.b_ih = b_ih; p.b_hh = b_hh; p.b_iht = b_iht; p.b_hht = b_hht;
    p.u1 = u1; p.u2 = u2; p.gy = gy; p.x = x;
    p.hseq = bar; p.bseq = bar + 256; p.tseq = bar + 512; p.claim = bar + 1024;
    p.hP0 = hP0; p.hP1 = hP1; p.htP0 = htP0; p.htP1 = htP1; p.bitsP = bitsP;
    p.ht_hi = ht_hi; p.ht_lo = ht_lo;
    p.Wih_hi  = wreg;             p.Wih_lo  = wreg + 1048576;
    p.Whh_hi  = wreg + 2097152;   p.Whh_lo  = wreg + 3145728;
    p.Wiht_hi = wreg + 4194304;   p.Wiht_lo = wreg + 5242880;
    p.Whht_hi = wreg + 6291456;   p.Whht_lo = wreg + 7340032;
    p.Wg_hi   = wreg + 8388608;   p.Wg_lo   = wreg + 9699328;
    p.em_hi   = wreg + 11272192;  p.em_lo   = wreg + 14450176;
    const ushort* Wl_hi = wreg + 11010048; const ushort* Wl_lo = wreg + 11141120;
    const ushort* y_hi  = wreg + 17628160; const ushort* y_lo  = wreg + 18152448;

    k_prep<<<dim3(38543), dim3(256), 0, stream>>>(W_ih, W_hh, W_iht, W_hht, Wg, Wlin,
                                                  emb, y, wreg, bar);
    k_gy<<<dim3(256), dim3(512), 0, stream>>>(y_hi, y_lo, p.Wg_hi, p.Wg_lo, bg, gy);

    void* args[] = {(void*)&p};
    hipLaunchCooperativeKernel((const void*)k_main, dim3(256), dim3(512), args, 0, stream);

    k_final<<<dim3(4, 4), dim3(256), 0, stream>>>(ht_hi, ht_lo, Wl_hi, Wl_lo, blin, out);
}

// Round 3
// 2252.864 us; speedup vs baseline: 1.2467x; 1.1496x over previous
//
#include <hip/hip_runtime.h>
#include <hip/hip_bf16.h>

// Doubly-recurrent LSTM + gumbel-sigmoid gate, B=256,T=64,H=512,V=6207,YF=2048.
// Persistent kernel; 16 independent row-group pipelines. XCD-aware dynamic role
// assignment pins each jb weight slice to one XCD (~2.2 MB < 4 MB L2).
// v4: c2 weights (Whht slice) parked in 128 VGPRs (removes 256KB/block/step of
// L2 weight traffic; c2 covers are now pure LDS+MFMA); unpack/Ac-build
// rewritten as b128 LDS ops (conflict floor); hs flag stored before Az unpack;
// emb staging moved after publish(bs) so emb misses drain at the counted
// vmcnt(2), not inside the bs flag chain. Bit-identical math to v3.

typedef __attribute__((ext_vector_type(8))) short short8;   // 8 bf16 = 1 MFMA operand
typedef __attribute__((ext_vector_type(4))) float floatx4;  // MFMA accumulator
typedef __attribute__((ext_vector_type(4))) unsigned int uintx4;

#define MFMA16(a, b, c) __builtin_amdgcn_mfma_f32_16x16x32_bf16(a, b, c, 0, 0, 0)
#define AGENT __HIP_MEMORY_SCOPE_AGENT
// s_getreg HWREG(XCC_ID=20, offset=0, size=32)  [measured: learn_hip m09]
#define HWREG_XCC_ID ((31u << 11) | (0u << 6) | 20u)

__device__ inline float bf2f(ushort u) {
    union { unsigned int u32; float f; } v; v.u32 = ((unsigned int)u) << 16; return v.f;
}
__device__ inline ushort f2bf(float f) {  // RNE, finite inputs only
    union { float f; unsigned int u; } v; v.f = f;
    return (ushort)((v.u + 0x7fffu + ((v.u >> 16) & 1u)) >> 16);
}
__device__ inline short8 ld8(const ushort* p) { return *(const short8*)p; }
__device__ inline float sigf(float x) { return 1.0f / (1.0f + expf(-x)); }
__device__ inline void mm3(floatx4& acc, short8 ah, short8 al, short8 bh, short8 bl) {
    acc = MFMA16(ah, bh, acc);
    acc = MFMA16(ah, bl, acc);
    acc = MFMA16(al, bh, acc);
}

// ---------------------------------------------------------------------------
// prep: split fp32 arrays into bf16 hi/lo in wreg; zero seqs/claim + state.
// ---------------------------------------------------------------------------
__global__ __launch_bounds__(256) void k_prep(const float* __restrict__ w0,
                                              const float* __restrict__ w1,
                                              const float* __restrict__ w2,
                                              const float* __restrict__ w3,
                                              const float* __restrict__ wg,
                                              const float* __restrict__ wl,
                                              const float* __restrict__ em,
                                              const float* __restrict__ yy,
                                              ushort* __restrict__ wreg,
                                              uint* __restrict__ zbase) {
    unsigned i = blockIdx.x * 256u + threadIdx.x;
    if (i >= 9866784u) return;
    if (i >= 9338368u) {
        zbase[i - 9338368u] = 0u;
        return;
    }
    const float* src; ushort* hi; unsigned n, loc;
    if (i < 4194304u) {
        unsigned seg = i >> 20; loc = i & 1048575u; n = 1048576u;
        hi = wreg + seg * 2097152u;
        src = (seg == 0) ? w0 : (seg == 1) ? w1 : (seg == 2) ? w2 : w3;
    } else if (i < 5505024u) { loc = i - 4194304u; src = wg; hi = wreg + 8388608u;  n = 1310720u; }
    else if (i < 5636096u)   { loc = i - 5505024u; src = wl; hi = wreg + 11010048u; n = 131072u; }
    else if (i < 8814080u)   { loc = i - 5636096u; src = em; hi = wreg + 11272192u; n = 3177984u; }
    else                     { loc = i - 8814080u; src = yy; hi = wreg + 17628160u; n = 524288u; }
    float v = src[loc];
    ushort h = f2bf(v);
    hi[loc] = h;
    hi[n + loc] = f2bf(v - bf2f(h));
}

// ---------------------------------------------------------------------------
// gy = y @ Wg[:,512:].T + bg  (M=256,N=512,K=2048; 256 blocks, 4-way K-split)
// ---------------------------------------------------------------------------
__global__ __launch_bounds__(512) void k_gy(const ushort* __restrict__ y_hi,
                                            const ushort* __restrict__ y_lo,
                                            const ushort* __restrict__ Wg_hi,
                                            const ushort* __restrict__ Wg_lo,
                                            const float* __restrict__ bg,
                                            float* __restrict__ gy) {
    __shared__ float zsB[4 * 528];
    int tid = threadIdx.x, lane = tid & 63, w = tid >> 6;
    int quad = lane >> 4, lr = lane & 15, q8 = quad * 8;
    int r0 = (blockIdx.x >> 4) * 16, n0 = (blockIdx.x & 15) * 32;
    int nh = w & 1, kq = w >> 1;
    int arow = r0 + lr, brow = n0 + nh * 16 + lr;
    floatx4 acc = {};
#pragma unroll
    for (int k0 = 0; k0 < 512; k0 += 32) {
        short8 ah = ld8(y_hi + arow * 2048 + kq * 512 + k0 + q8);
        short8 al = ld8(y_lo + arow * 2048 + kq * 512 + k0 + q8);
        short8 bh = ld8(Wg_hi + brow * 2560 + 512 + kq * 512 + k0 + q8);
        short8 bl = ld8(Wg_lo + brow * 2560 + 512 + kq * 512 + k0 + q8);
        mm3(acc, ah, al, bh, bl);
    }
#pragma unroll
    for (int r4 = 0; r4 < 4; r4++)
        zsB[kq * 528 + (quad * 4 + r4) * 33 + nh * 16 + lr] = acc[r4];
    __syncthreads();
    int ml = tid >> 5, jj = tid & 31;
    float s = zsB[ml * 33 + jj] + zsB[528 + ml * 33 + jj] +
              zsB[1056 + ml * 33 + jj] + zsB[1584 + ml * 33 + jj];
    gy[(r0 + ml) * 512 + n0 + jj] = s + bg[n0 + jj];
}

// ---------------------------------------------------------------------------
struct KP {
    const float *b_ih, *b_hh, *b_iht, *b_hht, *u1, *u2, *gy;
    const int* x;
    uint *hseq, *bseq, *tseq;         // 16 groups x 16 seq words (one line each)
    uint* claim;                      // 8 XCDs x 16-uint stride claim counters
    uint *hP0, *hP1, *htP0, *htP1, *bitsP;
    ushort *ht_hi, *ht_lo;
    const ushort *Whh_hi, *Whh_lo, *Wih_hi, *Wih_lo;
    const ushort *Wiht_hi, *Wiht_lo, *Whht_hi, *Whht_lo;
    const ushort *Wg_hi, *Wg_lo, *em_hi, *em_lo;
};

// Producer publish: drain own wave's stores, block-sync (=> all waves drained),
// then one seq store. Consumers poll; no two-sided barrier.
__device__ inline void publish(uint* sq, uint v) {
    asm volatile("" ::: "memory");
    __builtin_amdgcn_s_waitcnt(0);
    __syncthreads();
    if (threadIdx.x == 0)
        __hip_atomic_store(sq, v, __ATOMIC_RELAXED, AGENT);
}
__device__ inline void poll16(const uint* sq, uint target) {
    if ((threadIdx.x >> 6) == 0) {
        int l = threadIdx.x & 63;
        for (;;) {
            uint v = (l < 16) ? __hip_atomic_load(&sq[l], __ATOMIC_RELAXED, AGENT) : target;
            if (__all((int)(v >= target))) break;
            __builtin_amdgcn_s_sleep(1);
        }
    }
    __syncthreads();
}

// Issue 16 rows x 64B gather of a packed (hi|lo<<16) [256][512] buffer as
// 4 x dwordx4 per thread (device-coherent).
__device__ inline void issue_row16(const uint* __restrict__ src, int r0, uintx4* v) {
    int tid = threadIdx.x;
    int sr = tid >> 5, scol = (tid & 31) * 16;
    const uint* pp = src + (r0 + sr) * 512 + scol;
    asm volatile(
        "global_load_dwordx4 %0, %4, off sc0 sc1\n\t"
        "global_load_dwordx4 %1, %4, off offset:16 sc0 sc1\n\t"
        "global_load_dwordx4 %2, %4, off offset:32 sc0 sc1\n\t"
        "global_load_dwordx4 %3, %4, off offset:48 sc0 sc1"
        : "=v"(v[0]), "=v"(v[1]), "=v"(v[2]), "=v"(v[3])
        : "v"(pp) : "memory");
}
// Unpack packed dwords to hi/lo planes in registers; b128 LDS writes (conflict
// floor) instead of scalar dword writes.
__device__ inline void unpack_row16(const uintx4* v, ushort* __restrict__ dst) {
    int tid = threadIdx.x;
    int sr = tid >> 5, scol = (tid & 31) * 16;
    ushort* d = dst + sr * 1032 + scol;
    union { uint u[4]; short8 s; } H0, H1, L0, L1;
    H0.u[0] = (v[0][0] & 0xffffu) | (v[0][1] << 16);
    H0.u[1] = (v[0][2] & 0xffffu) | (v[0][3] << 16);
    H0.u[2] = (v[1][0] & 0xffffu) | (v[1][1] << 16);
    H0.u[3] = (v[1][2] & 0xffffu) | (v[1][3] << 16);
    L0.u[0] = (v[0][0] >> 16) | (v[0][1] & 0xffff0000u);
    L0.u[1] = (v[0][2] >> 16) | (v[0][3] & 0xffff0000u);
    L0.u[2] = (v[1][0] >> 16) | (v[1][1] & 0xffff0000u);
    L0.u[3] = (v[1][2] >> 16) | (v[1][3] & 0xffff0000u);
    H1.u[0] = (v[2][0] & 0xffffu) | (v[2][1] << 16);
    H1.u[1] = (v[2][2] & 0xffffu) | (v[2][3] << 16);
    H1.u[2] = (v[3][0] & 0xffffu) | (v[3][1] << 16);
    H1.u[3] = (v[3][2] & 0xffffu) | (v[3][3] << 16);
    L1.u[0] = (v[2][0] >> 16) | (v[2][1] & 0xffff0000u);
    L1.u[1] = (v[2][2] >> 16) | (v[2][3] & 0xffff0000u);
    L1.u[2] = (v[3][0] >> 16) | (v[3][1] & 0xffff0000u);
    L1.u[3] = (v[3][2] >> 16) | (v[3][3] & 0xffff0000u);
    *(short8*)(d) = H0.s;
    *(short8*)(d + 8) = H1.s;
    *(short8*)(d + 520) = L0.s;
    *(short8*)(d + 520 + 8) = L1.s;
}

// Stage 16 emb rows (hi/lo planes, plain cached loads) into LDS, As layout.
__device__ inline void stage_emb(const ushort* __restrict__ emh,
                                 const ushort* __restrict__ eml,
                                 const int* __restrict__ x, int r0, int t,
                                 ushort* __restrict__ dst) {
    int tid = threadIdx.x;
    int sr = tid >> 5, sc = (tid & 31) * 16;
    int tok = x[(r0 + sr) * 64 + t];
    const short8* ph = (const short8*)(emh + (size_t)tok * 512 + sc);
    const short8* pl = (const short8*)(eml + (size_t)tok * 512 + sc);
    short8 h0 = ph[0], h1 = ph[1], l0 = pl[0], l1 = pl[1];
    ushort* d = dst + sr * 1032;
    *(short8*)(d + sc) = h0;       *(short8*)(d + sc + 8) = h1;
    *(short8*)(d + 520 + sc) = l0; *(short8*)(d + 520 + sc + 8) = l1;
}

__device__ inline short8 fragA(const ushort* As, int row, int k) {
    return *(const short8*)(As + row * 1032 + k);
}

__global__ void __launch_bounds__(512, 1) k_main(KP p) {
    __shared__ ushort As[16 * 1032];   // h(t) full tile (serves B(t) and A(t+1))
    __shared__ ushort Ae[16 * 1032];   // emb rows for current t
    __shared__ ushort Az[16 * 1032];   // ht(t-1) tile
    __shared__ ushort Ac[16 * 1032];   // hf tile, rebuilt locally = As & gate bits
    __shared__ float zsD[4224];        // [0:2112] a1/zsB/c1 ; [2112:4224] a2/c2
    __shared__ uint gbits[256];        // gate bits: 16 rows x 16 words
    __shared__ uint role_s;

    const int tid = threadIdx.x;           // 0..511
    const int w = tid >> 6;                // wave 0..7
    const int lane = tid & 63;
    const int quad = lane >> 4;
    const int lr = lane & 15;
    const int q8 = quad * 8;
    const float EPS = 1e-10f;

    if (tid == 0) {
        uint xcc = __builtin_amdgcn_s_getreg(HWREG_XCC_ID) & 7u;
        uint slot = __hip_atomic_fetch_add(&p.claim[xcc * 16], 1u,
                                           __ATOMIC_RELAXED, AGENT) & 31u;
        role_s = xcc * 32u + slot;
    }
    __syncthreads();
    const uint role = role_s;
    const int jb = (int)(role >> 4);       // xcc*2 + (slot>>4)
    const int g16 = (int)(role & 15u);
    const int r0 = g16 * 16, j0 = jb * 32;

    const int g4 = w & 3, team = w >> 2;
    const int gate = w >> 1, nh = w & 1;
    const int brow = gate * 512 + j0 + nh * 16 + lr;   // c1/c2 weight row
    const int kq = w >> 1;                              // stage B K-split window
    const int browB = j0 + nh * 16 + lr;                // stage B Wg row
    const int ml = tid >> 5, jj = tid & 31;             // epilogue element

    const float biasAe0 = p.b_ih[j0 + jj]        + p.b_hh[j0 + jj];
    const float biasAe1 = p.b_ih[512 + j0 + jj]  + p.b_hh[512 + j0 + jj];
    const float biasAe2 = p.b_ih[1024 + j0 + jj] + p.b_hh[1024 + j0 + jj];
    const float biasAe3 = p.b_ih[1536 + j0 + jj] + p.b_hh[1536 + j0 + jj];
    const float biasCe0 = p.b_iht[j0 + jj]        + p.b_hht[j0 + jj];
    const float biasCe1 = p.b_iht[512 + j0 + jj]  + p.b_hht[512 + j0 + jj];
    const float biasCe2 = p.b_iht[1024 + j0 + jj] + p.b_hht[1024 + j0 + jj];
    const float biasCe3 = p.b_iht[1536 + j0 + jj] + p.b_hht[1536 + j0 + jj];
    const float gy_r = p.gy[(r0 + ml) * 512 + j0 + jj];

    const int rowA = g4 * 512 + j0 + lr;               // team-A weight base row
    const ushort* WAh = (team ? p.Wih_hi : p.Whh_hi) + rowA * 512;
    const ushort* WAl = (team ? p.Wih_lo : p.Whh_lo) + rowA * 512;
    const ushort* WitH = p.Wiht_hi + brow * 512;       // c1
    const ushort* WitL = p.Wiht_lo + brow * 512;
    const ushort* WgH = p.Wg_hi + browB * 2560 + kq * 128;
    const ushort* WgL = p.Wg_lo + browB * 2560 + kq * 128;
    const float* pu1 = p.u1 + (r0 + ml) * 512 + j0 + jj;
    const float* pu2 = p.u2 + (r0 + ml) * 512 + j0 + jj;
    uint* hs = p.hseq + g16 * 16;      // this group's 64B seq lines
    uint* bs = p.bseq + g16 * 16;
    uint* hts = p.tseq + g16 * 16;

    // ---- park c2 (Whht slice) weights in registers: 16 k-subtiles x hi/lo ---
    short8 wHt[16], wLt[16];
    {
        const ushort* WhtH = p.Whht_hi + brow * 512;
        const ushort* WhtL = p.Whht_lo + brow * 512;
#pragma unroll
        for (int kk = 0; kk < 16; kk++) {
            wHt[kk] = ld8(WhtH + kk * 32 + q8);
            wLt[kk] = ld8(WhtL + kk * 32 + q8);
        }
    }

    // init: h(-1) = 0 in As; emb rows for t=0 into Ae; U(0) prefetch
    for (int i = tid; i < 16 * 1032; i += 512) As[i] = 0;
    stage_emb(p.em_hi, p.em_lo, p.x, r0, 0, Ae);
    float U1 = __builtin_nontemporal_load(pu1);
    float U2 = __builtin_nontemporal_load(pu2);
    __syncthreads();

    float c_reg = 0.0f, ct_reg = 0.0f;

    for (int t = 0; t < 64; t++) {
        // ==== Stage A (team-split): a1 = h@Whh.T (L), a2 = emb@Wih.T (H) =====
        {
            const ushort* Ax = team ? Ae : As;
            floatx4 acc0 = {}, acc1 = {};
#pragma unroll
            for (int k0 = 0; k0 < 512; k0 += 32) {
                short8 xh = fragA(Ax, lr, k0 + q8);
                short8 xl = fragA(Ax, lr, 520 + k0 + q8);
                mm3(acc0, xh, xl, ld8(WAh + k0 + q8), ld8(WAl + k0 + q8));
                mm3(acc1, xh, xl, ld8(WAh + 8192 + k0 + q8), ld8(WAl + 8192 + k0 + q8));
            }
#pragma unroll
            for (int r4 = 0; r4 < 4; r4++) {
                zsD[team * 2112 + (quad * 4 + r4) * 132 + g4 * 32 + lr]      = acc0[r4];
                zsD[team * 2112 + (quad * 4 + r4) * 132 + g4 * 32 + 16 + lr] = acc1[r4];
            }
        }
        // tseq flags propagated during stage A -> poll is ~instant; its
        // syncthreads doubles as the zsD visibility barrier.
        if (t > 0) poll16(hts, (uint)t); else __syncthreads();
        uintx4 vz[4];
        issue_row16((t & 1) ? p.htP0 : p.htP1, r0, vz);   // ht(t-1); RT hidden
        // ==== epi-A ====
        uint* hPcur = (t & 1) ? p.hP1 : p.hP0;   // double-buffered
        {
            float zi = (zsD[ml * 132 + jj]      + zsD[2112 + ml * 132 + jj])      + biasAe0;
            float zf = (zsD[ml * 132 + 32 + jj] + zsD[2112 + ml * 132 + 32 + jj]) + biasAe1;
            float zg = (zsD[ml * 132 + 64 + jj] + zsD[2112 + ml * 132 + 64 + jj]) + biasAe2;
            float zo = (zsD[ml * 132 + 96 + jj] + zsD[2112 + ml * 132 + 96 + jj]) + biasAe3;
            c_reg = sigf(zf) * c_reg + sigf(zi) * tanhf(zg);
            float hv = sigf(zo) * tanhf(c_reg);
            ushort hb = f2bf(hv);
            ushort lb = f2bf(hv - bf2f(hb));
            __hip_atomic_store(&hPcur[(r0 + ml) * 512 + j0 + jj],
                               (uint)hb | ((uint)lb << 16), __ATOMIC_RELAXED, AGENT);
        }
        // ---- drain h stores + vz; flag FIRST, then unpack (overlaps props) --
        asm volatile("s_waitcnt vmcnt(0)" ::: "memory");
        __builtin_amdgcn_sched_barrier(0);
        __syncthreads();
        if (tid == 0)
            __hip_atomic_store(&hs[jb], (uint)(t + 1), __ATOMIC_RELAXED, AGENT);
        unpack_row16(vz, Az);
        // noise for this step (U prefetched at t-1) -- pure VALU cover
        float noise = -logf(logf(U2 + EPS) / logf(U1 + EPS) + EPS);
        __syncthreads();                  // Az visible to all waves
        // c2 p1 (kk 0..5): covers hs flag propagation (reg weights, LDS only)
        floatx4 c2acc = {};
#pragma unroll
        for (int kk = 0; kk < 6; kk++)
            mm3(c2acc, fragA(Az, lr, kk * 32 + q8), fragA(Az, lr, 520 + kk * 32 + q8),
                wHt[kk], wLt[kk]);
        poll16(hs, (uint)(t + 1));
        uintx4 va[4];
        issue_row16(hPcur, r0, va);                        // h(t) full
        // c2 p2 (kk 6..11): covers As gather RT
#pragma unroll
        for (int kk = 6; kk < 12; kk++)
            mm3(c2acc, fragA(Az, lr, kk * 32 + q8), fragA(Az, lr, 520 + kk * 32 + q8),
                wHt[kk], wLt[kk]);
        asm volatile("s_waitcnt vmcnt(0)" ::: "memory");
        __builtin_amdgcn_sched_barrier(0);
        unpack_row16(va, As);
        __syncthreads();

        // ==== Stage B: gate logits -> gate bits (published, 64B/block) =======
        {
            floatx4 acc = {};
#pragma unroll
            for (int k0 = 0; k0 < 128; k0 += 32)
                mm3(acc, fragA(As, lr, kq * 128 + k0 + q8),
                    fragA(As, lr, 520 + kq * 128 + k0 + q8),
                    ld8(WgH + k0 + q8), ld8(WgL + k0 + q8));
#pragma unroll
            for (int r4 = 0; r4 < 4; r4++)
                zsD[kq * 528 + (quad * 4 + r4) * 33 + nh * 16 + lr] = acc[r4];
        }
        __syncthreads();
        {
            float z2 = zsD[ml * 33 + jj] + zsD[528 + ml * 33 + jj] +
                       zsD[1056 + ml * 33 + jj] + zsD[1584 + ml * 33 + jj];
            float logit = fmaxf(z2 + gy_r, 0.0f);
            bool gbit = sigf(logit + noise) >= 0.5f;
            unsigned long long bm = __ballot((int)gbit);
            if ((lane & 31) == 0)
                __hip_atomic_store(&p.bitsP[(r0 + ml) * 16 + jb],
                                   (uint)(bm >> ((lane >> 5) * 32)),
                                   __ATOMIC_RELAXED, AGENT);
        }
        publish(&bs[jb], (uint)(t + 1));
        // emb(t+1) AFTER publish: its miss latency drains at the counted vmcnt
        if (t < 63) stage_emb(p.em_hi, p.em_lo, p.x, r0, t + 1, Ae);
        // c2 p3 (kk 12..15): covers bs flag propagation
#pragma unroll
        for (int kk = 12; kk < 16; kk++)
            mm3(c2acc, fragA(Az, lr, kk * 32 + q8), fragA(Az, lr, 520 + kk * 32 + q8),
                wHt[kk], wLt[kk]);
#pragma unroll
        for (int r4 = 0; r4 < 4; r4++)
            zsD[2112 + (quad * 4 + r4) * 132 + gate * 32 + nh * 16 + lr] = c2acc[r4];
        poll16(bs, (uint)(t + 1));
        uint rb = 0;
        if (tid < 256)
            asm volatile("global_load_dword %0, %1, off sc0 sc1"
                         : "=v"(rb) : "v"(p.bitsP + r0 * 16 + tid) : "memory");
        if (t < 63) {   // U prefetch for t+1 after the bits load -> counted wait
            U1 = __builtin_nontemporal_load(pu1 + (t + 1) * 131072);
            U2 = __builtin_nontemporal_load(pu2 + (t + 1) * 131072);
            asm volatile("s_waitcnt vmcnt(2)" ::: "memory");
        } else {
            asm volatile("s_waitcnt vmcnt(0)" ::: "memory");
        }
        __builtin_amdgcn_sched_barrier(0);
        if (tid < 256) gbits[tid] = rb;
        __syncthreads();
        // build Ac = As & mask, b128 ops (bit-exact hf: gate 0/1 on hi/lo pair)
        {
            int sr = tid >> 5, sc = (tid & 31) * 16;
            uint word = gbits[sr * 16 + (sc >> 5)];
            uint chunk = (word >> (sc & 16)) & 0xffffu;
            const ushort* as0 = As + sr * 1032 + sc;
            ushort* ac0 = Ac + sr * 1032 + sc;
            union { uint u[4]; short8 s; } m0, m1;
#pragma unroll
            for (int j = 0; j < 4; j++) {
                uint b0 = 0u - ((chunk >> (2 * j)) & 1u);
                uint b1 = 0u - ((chunk >> (2 * j + 1)) & 1u);
                m0.u[j] = (b0 & 0xffffu) | (b1 << 16);
            }
#pragma unroll
            for (int j = 0; j < 4; j++) {
                uint b0 = 0u - ((chunk >> (8 + 2 * j)) & 1u);
                uint b1 = 0u - ((chunk >> (8 + 2 * j + 1)) & 1u);
                m1.u[j] = (b0 & 0xffffu) | (b1 << 16);
            }
            short8 h0 = *(const short8*)(as0);
            short8 h1 = *(const short8*)(as0 + 8);
            short8 l0 = *(const short8*)(as0 + 520);
            short8 l1 = *(const short8*)(as0 + 528);
            *(short8*)(ac0)       = h0 & m0.s;
            *(short8*)(ac0 + 8)   = h1 & m1.s;
            *(short8*)(ac0 + 520) = l0 & m0.s;
            *(short8*)(ac0 + 528) = l1 & m1.s;
        }
        __syncthreads();
        // ==== c1 = hf@Wiht.T (all 8 waves) ===================================
        {
            floatx4 c1acc = {};
#pragma unroll
            for (int k0 = 0; k0 < 512; k0 += 32)
                mm3(c1acc, fragA(Ac, lr, k0 + q8), fragA(Ac, lr, 520 + k0 + q8),
                    ld8(WitH + k0 + q8), ld8(WitL + k0 + q8));
#pragma unroll
            for (int r4 = 0; r4 < 4; r4++)
                zsD[(quad * 4 + r4) * 132 + gate * 32 + nh * 16 + lr] = c1acc[r4];
        }
        __syncthreads();
        // ==== epi-C ====
        {
            float zi = (zsD[ml * 132 + jj]      + zsD[2112 + ml * 132 + jj])      + biasCe0;
            float zf = (zsD[ml * 132 + 32 + jj] + zsD[2112 + ml * 132 + 32 + jj]) + biasCe1;
            float zg = (zsD[ml * 132 + 64 + jj] + zsD[2112 + ml * 132 + 64 + jj]) + biasCe2;
            float zo = (zsD[ml * 132 + 96 + jj] + zsD[2112 + ml * 132 + 96 + jj]) + biasCe3;
            ct_reg = sigf(zf) * ct_reg + sigf(zi) * tanhf(zg);
            float hv = sigf(zo) * tanhf(ct_reg);
            ushort hb = f2bf(hv);
            ushort lb = f2bf(hv - bf2f(hb));
            int idx = (r0 + ml) * 512 + j0 + jj;
            uint* htcur = (t & 1) ? p.htP1 : p.htP0;
            __hip_atomic_store(&htcur[idx], (uint)hb | ((uint)lb << 16),
                               __ATOMIC_RELAXED, AGENT);
            if (t == 63) { p.ht_hi[idx] = hb; p.ht_lo[idx] = lb; }
        }
        publish(&hts[jb], (uint)(t + 1));  // drains ht stores; sync guards LDS reuse
    }
}

// ---------------------------------------------------------------------------
// out = relu(ht @ Wlin.T + blin)  (M=256,N=256,K=512 hi/lo) -> fp32
// ---------------------------------------------------------------------------
__global__ __launch_bounds__(256) void k_final(const ushort* __restrict__ ht_hi,
                                               const ushort* __restrict__ ht_lo,
                                               const ushort* __restrict__ Wl_hi,
                                               const ushort* __restrict__ Wl_lo,
                                               const float* __restrict__ blin,
                                               float* __restrict__ out) {
    int tid = threadIdx.x, lane = tid & 63, w = tid >> 6;
    int wm = w & 1, wn = w >> 1, quad = lane >> 4, lr = lane & 15;
    int m0 = blockIdx.y * 64, n0 = blockIdx.x * 64;
    floatx4 acc[2][2] = {};
    for (int k0 = 0; k0 < 512; k0 += 32) {
        short8 ah[2], al[2], bh[2], bl[2];
#pragma unroll
        for (int tn = 0; tn < 2; tn++) {
            int n = n0 + wn * 32 + tn * 16 + lr;
            bh[tn] = ld8(Wl_hi + n * 512 + k0 + quad * 8);
            bl[tn] = ld8(Wl_lo + n * 512 + k0 + quad * 8);
        }
#pragma unroll
        for (int tm = 0; tm < 2; tm++) {
            int r = m0 + wm * 32 + tm * 16 + lr;
            ah[tm] = ld8(ht_hi + r * 512 + k0 + quad * 8);
            al[tm] = ld8(ht_lo + r * 512 + k0 + quad * 8);
        }
#pragma unroll
        for (int tm = 0; tm < 2; tm++)
#pragma unroll
            for (int tn = 0; tn < 2; tn++) mm3(acc[tm][tn], ah[tm], al[tm], bh[tn], bl[tn]);
    }
#pragma unroll
    for (int tm = 0; tm < 2; tm++)
#pragma unroll
        for (int tn = 0; tn < 2; tn++)
#pragma unroll
            for (int r4 = 0; r4 < 4; r4++) {
                int row = m0 + wm * 32 + tm * 16 + quad * 4 + r4;
                int n = n0 + wn * 32 + tn * 16 + lr;
                out[row * 256 + n] = fmaxf(acc[tm][tn][r4] + blin[n], 0.0f);
            }
}

// ---------------------------------------------------------------------------
extern "C" void kernel_launch(void* const* d_in, const int* in_sizes, int n_in,
                              void* d_out, int out_size, void* d_ws, size_t ws_size,
                              hipStream_t stream) {
    (void)in_sizes; (void)n_in; (void)out_size; (void)ws_size;
    const float* y      = (const float*)d_in[0];
    const int*   x      = (const int*)d_in[1];
    const float* emb    = (const float*)d_in[2];
    const float* W_ih   = (const float*)d_in[3];
    const float* W_hh   = (const float*)d_in[4];
    const float* b_ih   = (const float*)d_in[5];
    const float* b_hh   = (const float*)d_in[6];
    const float* W_iht  = (const float*)d_in[7];
    const float* W_hht  = (const float*)d_in[8];
    const float* b_iht  = (const float*)d_in[9];
    const float* b_hht  = (const float*)d_in[10];
    const float* Wg     = (const float*)d_in[11];
    const float* bg     = (const float*)d_in[12];
    const float* Wlin   = (const float*)d_in[13];
    const float* blin   = (const float*)d_in[14];
    const float* u1     = (const float*)d_in[15];
    const float* u2     = (const float*)d_in[16];
    float* out = (float*)d_out;

    // ws layout (uints): bar[4128]=hseq(256)|bseq(256)|tseq(256)|pad|claim(+1024)
    //                    hP0 hP1 htP0 htP1 [4x131072]  (zeroed with bar)
    //                    gy[131072 f32] ht_hi/ht_lo[131072 us] bitsP[4096] wreg
    uint* bar  = (uint*)d_ws;
    uint* hP0  = bar + 4128;
    uint* hP1  = hP0 + 131072;
    uint* htP0 = hP1 + 131072;
    uint* htP1 = htP0 + 131072;
    float* gy  = (float*)(htP1 + 131072);
    ushort* ht_hi = (ushort*)(gy + 131072);
    ushort* ht_lo = ht_hi + 131072;
    uint* bitsP = (uint*)(ht_lo + 131072);
    ushort* wreg = (ushort*)(bitsP + 4096);

    KP p;
    p.b_ih = b_ih; p.b_hh = b_hh; p.b_iht = b_iht; p.b_hht = b_hht;
    p.u1 = u1; p.u2 = u2; p.gy = gy; p.x = x;
    p.hseq = bar; p.bseq = bar + 256; p.tseq = bar + 512; p.claim = bar + 1024;
    p.hP0 = hP0; p.hP1 = hP1; p.htP0 = htP0; p.htP1 = htP1; p.bitsP = bitsP;
    p.ht_hi = ht_hi; p.ht_lo = ht_lo;
    p.Wih_hi  = wreg;             p.Wih_lo  = wreg + 1048576;
    p.Whh_hi  = wreg + 2097152;   p.Whh_lo  = wreg + 3145728;
    p.Wiht_hi = wreg + 4194304;   p.Wiht_lo = wreg + 5242880;
    p.Whht_hi = wreg + 6291456;   p.Whht_lo = wreg + 7340032;
    p.Wg_hi   = wreg + 8388608;   p.Wg_lo   = wreg + 9699328;
    p.em_hi   = wreg + 11272192;  p.em_lo   = wreg + 14450176;
    const ushort* Wl_hi = wreg + 11010048; const ushort* Wl_lo = wreg + 11141120;
    const ushort* y_hi  = wreg + 17628160; const ushort* y_lo  = wreg + 18152448;

    k_prep<<<dim3(38543), dim3(256), 0, stream>>>(W_ih, W_hh, W_iht, W_hht, Wg, Wlin,
                                                  emb, y, wreg, bar);
    k_gy<<<dim3(256), dim3(512), 0, stream>>>(y_hi, y_lo, p.Wg_hi, p.Wg_lo, bg, gy);

    void* args[] = {(void*)&p};
    hipLaunchCooperativeKernel((const void*)k_main, dim3(256), dim3(512), args, 0, stream);

    k_final<<<dim3(4, 4), dim3(256), 0, stream>>>(ht_hi, ht_lo, Wl_hi, Wl_lo, blin, out);
}